// Round 7
// baseline (167.335 us; speedup 1.0000x reference)
//
#include <hip/hip_runtime.h>
#include <hip/hip_bf16.h>

typedef __attribute__((ext_vector_type(8))) short short8;
typedef __attribute__((ext_vector_type(4))) float floatx4;

// Problem constants: T=1024, B=4, E=1024, H=16, D=64, L=16
// Inputs/outputs fp32; internals bf16 MFMA with fp32 accumulation.
// Softmax runs in the exp2 domain: q is pre-scaled by 0.125*log2(e), so
// scores (qk + rel-bias) are already in log2 units and p = exp2(s).

#define QSCALE 0.18033688011112043f   // 0.125 * log2(e)

__device__ __forceinline__ short f2bf(float x) {
  union { float f; unsigned u; } cv; cv.f = x;
  unsigned u = cv.u + (0x7FFFu + ((cv.u >> 16) & 1u));  // RNE
  return (short)(u >> 16);
}

// gfx950 v_cvt_pk_bf16_f32 via hip_bf16 API: 1 VALU op per 2 values.
__device__ __forceinline__ unsigned pk_bf16(float a, float b) {
  union { __hip_bfloat162 h; unsigned u; } cv;
  cv.h = __float22bfloat162_rn(make_float2(a, b));
  return cv.u;
}

// v_exp_f32 computes 2^x directly.
__device__ __forceinline__ float exp2_hw(float x) {
  return __builtin_amdgcn_exp2f(x);
}

__device__ __forceinline__ floatx4 mfma16(short8 a, short8 b, floatx4 c) {
  return __builtin_amdgcn_mfma_f32_16x16x32_bf16(a, b, c, 0, 0, 0);
}

__device__ __forceinline__ void async_copy16(const void* g, void* l) {
  __builtin_amdgcn_global_load_lds((const __attribute__((address_space(1))) void*)g,
                                   (__attribute__((address_space(3))) void*)l, 16, 0, 0);
}

// ---------------------------------------------------------------------------
// Kernel 0: fp32 -> bf16 for query / in_proj_weight / out_w in ONE launch.
// query is ALSO transposed (T,B,E) -> (B,T,E).
// ---------------------------------------------------------------------------
__global__ void __launch_bounds__(256) convert_all_kernel(
    const float* __restrict__ s0, const float* __restrict__ s1,
    const float* __restrict__ s2,
    short* __restrict__ d0, short* __restrict__ d1, short* __restrict__ d2)
{
  int i = blockIdx.x * 256 + threadIdx.x;
  if (i < 524288) {               // query with transpose
    int e8 = i & 127, b = (i >> 7) & 3, t = i >> 9;
    const float4* s = (const float4*)s0 + (size_t)i * 2;
    float4 a = s[0], c = s[1];
    uint4 o = make_uint4(pk_bf16(a.x, a.y), pk_bf16(a.z, a.w),
                         pk_bf16(c.x, c.y), pk_bf16(c.z, c.w));
    *(uint4*)(d0 + (size_t)b * 1048576 + t * 1024 + e8 * 8) = o;
  } else {                        // weights, straight copy
    const float* src; short* dst; int off;
    if (i < 917504) { src = s1; dst = d1; off = i - 524288; }
    else            { src = s2; dst = d2; off = i - 917504; }
    const float4* s = (const float4*)src + (size_t)off * 2;
    float4 a = s[0], c = s[1];
    uint4 o = make_uint4(pk_bf16(a.x, a.y), pk_bf16(a.z, a.w),
                         pk_bf16(c.x, c.y), pk_bf16(c.z, c.w));
    *(uint4*)(dst + (size_t)off * 8) = o;
  }
}

// ---------------------------------------------------------------------------
// Kernel 1: qkv = query_bt @ in_proj_weight^T + bias.
// 256x192 tile, BK=64, 8 waves (2Mx4N; per-wave 128x48), grid (16,16) = 256
// blocks = exactly 1 per CU (full machine, LDS 112 KB).
// Simple proven 2-phase pipeline: per K-tile
//   {7x global_load_lds (nxt) | 22x ds_read_b128 (cur) | 48 MFMA |
//    vmcnt(0) | s_barrier}
// xor-8 swizzled LDS (conflict-free b128 reads). 'which' (q/k/v) is
// resolved per-nt (16-wide, uniform).
// ---------------------------------------------------------------------------
__global__ void __launch_bounds__(512, 2) gemm_qkv(
    const short* __restrict__ A, const short* __restrict__ W,
    const float* __restrict__ bias,
    short* __restrict__ q_ws, short* __restrict__ k_ws, short* __restrict__ v_ws)
{
  __shared__ __align__(16) short Atile[2 * 256 * 64];   // 64 KB
  __shared__ __align__(16) short Btile[2 * 192 * 64];   // 48 KB
  const int tid = threadIdx.x, lane = tid & 63, w = tid >> 6;
  const int quad = lane >> 4, l16 = lane & 15;
  const int m0 = blockIdx.x * 256, n0 = blockIdx.y * 192;
  const int wmh = (w >> 2);             // 0/1: which 128-row half of A tile
  const int wn = (w & 3) * 48;          // wave's 48-col window in B tile

  const short* Ag = A + (size_t)m0 * 1024;
  const short* Wg = W + (size_t)n0 * 1024;

  floatx4 acc[8][3];
  #pragma unroll
  for (int mt = 0; mt < 8; mt++)
    #pragma unroll
    for (int nt = 0; nt < 3; nt++) acc[mt][nt] = (floatx4)(0.0f);

  // A: 256x64 bf16 = 2048 16B-segs -> 4 loads/thread.
  // B: 192x64 bf16 = 1536 16B-segs -> 3 loads/thread.
  // seg s: row = s>>3, slot p = s&7 holds global chunk ck = p^(row&7).
  #define STAGE_A(kc, buf)                                                   \
    {                                                                        \
      _Pragma("unroll")                                                      \
      for (int i = 0; i < 4; i++) {                                          \
        int seg = i * 512 + tid;                                             \
        int row = seg >> 3, p = seg & 7;                                     \
        int ck = p ^ (row & 7);                                              \
        async_copy16(Ag + (size_t)row * 1024 + (kc) * 64 + ck * 8,           \
                     Atile + (buf) * 16384 + (size_t)(i * 512 + w * 64) * 8);\
      }                                                                      \
    }
  #define STAGE_B(kc, buf)                                                   \
    {                                                                        \
      _Pragma("unroll")                                                      \
      for (int i = 0; i < 3; i++) {                                          \
        int seg = i * 512 + tid;                                             \
        int row = seg >> 3, p = seg & 7;                                     \
        int ck = p ^ (row & 7);                                              \
        async_copy16(Wg + (size_t)row * 1024 + (kc) * 64 + ck * 8,           \
                     Btile + (buf) * 12288 + (size_t)(i * 512 + w * 64) * 8);\
      }                                                                      \
    }

  STAGE_A(0, 0); STAGE_B(0, 0);
  asm volatile("s_waitcnt vmcnt(0)" ::: "memory");
  __builtin_amdgcn_s_barrier();

  for (int kt = 0; kt < 16; ++kt) {
    const int cur = kt & 1, nxt = cur ^ 1;
    const int kc1 = (kt + 1 < 16) ? kt + 1 : 15;   // ghost re-stage on tail

    // ---- prefetch next tile FIRST (lands while we read + MFMA) ----
    STAGE_A(kc1, nxt); STAGE_B(kc1, nxt);

    // ---- all fragment reads for this tile (22 x ds_read_b128) ----
    short8 af[8][2], bf[3][2];
    #pragma unroll
    for (int mt = 0; mt < 8; mt++) {
      int r = mt * 16 + l16;                        // 0..127 in wave's half
      int gr = wmh * 128 + r;                       // global A-tile row
      #pragma unroll
      for (int ks = 0; ks < 2; ks++)
        af[mt][ks] = *(const short8*)(Atile + cur * 16384 + gr * 64
                                      + (((quad + 4 * ks) ^ (r & 7)) << 3));
    }
    #pragma unroll
    for (int nt = 0; nt < 3; nt++) {
      int row = wn + nt * 16 + l16;                 // 0..191 (wn mult of 48)
      #pragma unroll
      for (int ks = 0; ks < 2; ks++)
        bf[nt][ks] = *(const short8*)(Btile + cur * 12288 + row * 64
                                      + (((quad + 4 * ks) ^ (row & 7)) << 3));
    }

    // ---- 48 MFMA ----
    __builtin_amdgcn_s_setprio(1);
    #pragma unroll
    for (int mt = 0; mt < 8; mt++)
      #pragma unroll
      for (int nt = 0; nt < 3; nt++)
        #pragma unroll
        for (int ks = 0; ks < 2; ks++)
          acc[mt][nt] = mfma16(af[mt][ks], bf[nt][ks], acc[mt][nt]);
    __builtin_amdgcn_s_setprio(0);
    __builtin_amdgcn_sched_barrier(0);

    asm volatile("s_waitcnt vmcnt(0)" ::: "memory");   // nxt landed
    __builtin_amdgcn_s_barrier();
  }
  #undef STAGE_A
  #undef STAGE_B

  // ---- epilogue: which (q/k/v) resolved per nt (16-wide, uniform) ----
  #pragma unroll
  for (int nt = 0; nt < 3; nt++) {
    int f = n0 + wn + nt * 16 + l16;          // 0..3071
    float bv = bias[f];
    int which = f >> 10;                      // 0=q 1=k 2=v
    int h = (f >> 6) & 15;
    int d = f & 63;
    if (which == 2) {
      #pragma unroll
      for (int mt = 0; mt < 8; mt++) {
        int r0 = m0 + wmh * 128 + mt * 16 + quad * 4;   // row = b*1024 + t
        int t = r0 & 1023, bb = r0 >> 10;
        int bh = bb * 16 + h;
        unsigned lo = pk_bf16(acc[mt][nt][0] + bv, acc[mt][nt][1] + bv);
        unsigned hi = pk_bf16(acc[mt][nt][2] + bv, acc[mt][nt][3] + bv);
        *(uint2*)(v_ws + ((size_t)bh * 64 + d) * 1024 + t) = make_uint2(lo, hi);
      }
    } else {
      short* dst = which ? k_ws : q_ws;
      const float sc = which ? 1.0f : QSCALE;
      #pragma unroll
      for (int mt = 0; mt < 8; mt++) {
        int r0 = m0 + wmh * 128 + mt * 16 + quad * 4;
        int t = r0 & 1023, bb = r0 >> 10;
        int bh = bb * 16 + h;
        unsigned u01 = pk_bf16((acc[mt][nt][0] + bv) * sc, (acc[mt][nt][1] + bv) * sc);
        unsigned u23 = pk_bf16((acc[mt][nt][2] + bv) * sc, (acc[mt][nt][3] + bv) * sc);
        size_t base = ((size_t)bh * 1024 + t) * 64 + d;
        dst[base]           = (short)u01;
        dst[base + 64]      = (short)(u01 >> 16);
        dst[base + 128]     = (short)u23;
        dst[base + 192]     = (short)(u23 >> 16);
      }
    }
  }
}

// ---------------------------------------------------------------------------
// Kernel 2: flash-style attention, S^T formulation.
// 8 waves x 32 q-rows (2 q-groups/wave), grid 256 = 1 block/CU.
// K/V LDS reads amortized over 2 q-groups: per-CU LDS-pipe cycles/tile
// drop ~43% vs the 16-wave/16-q layout. Keeps the R6 diet: bias-folded
// QK C-init, ones-MFMA row-sum (no shfl reduce), per-nt streaming.
// LDS 97 KB: rel 256x33 f32 + K/V dbuf + p_lds[8][2qt].
//  - exp2-domain softmax; T5 setprio around MFMA clusters.
// ---------------------------------------------------------------------------
__global__ void __launch_bounds__(512, 2) attn_kernel(
    const short* __restrict__ q_ws, const short* __restrict__ k_ws,
    const short* __restrict__ v_ws, const float* __restrict__ relk,
    short* __restrict__ attn_ws)
{
  __shared__ float rel_lds[256 * 33];                   // 33792 B
  __shared__ __align__(16) short Ktile[2][64 * 64];     // 16384 B
  __shared__ __align__(16) short Vtile[2][64 * 64];     // 16384 B
  __shared__ __align__(16) short p_lds[16][16 * 64];    // 32768 B
  const int tid = threadIdx.x, lane = tid & 63, w = tid >> 6;  // w 0..7
  const int quad = lane >> 4, l16 = lane & 15;
  // XCD swizzle: head = 8*(blk&7) + (blk>>3)&7, chunk = blk>>6 (0..3)
  const int bh = 8 * ((int)blockIdx.x & 7) + (((int)blockIdx.x >> 3) & 7);
  const int t0 = ((int)blockIdx.x >> 6) * 256;
  const int b = bh >> 4, h = bh & 15;

  // Q fragments: q-row(qt) = t0 + qt*128 + w*16 + l16
  short8 aq[2][2];
  #pragma unroll
  for (int qt = 0; qt < 2; qt++)
    #pragma unroll
    for (int ks = 0; ks < 2; ks++)
      aq[qt][ks] = *(const short8*)(q_ws
          + ((size_t)bh * 1024 + t0 + qt * 128 + w * 16 + l16) * 64
          + ks * 32 + quad * 8);

  // ---- stage relk[0:33][0:64] as bf16 into Ktile[0] (xor-swizzled, pad 48)
  if (tid < 384) {
    int row = tid >> 3, p = tid & 7;
    short8 val;
    if (row < 33) {
      const float* src = relk + row * 1024 + p * 8;
      float4 a = *(const float4*)src, c = *(const float4*)(src + 4);
      val[0] = f2bf(a.x); val[1] = f2bf(a.y); val[2] = f2bf(a.z); val[3] = f2bf(a.w);
      val[4] = f2bf(c.x); val[5] = f2bf(c.y); val[6] = f2bf(c.z); val[7] = f2bf(c.w);
    } else {
      val = (short8)0;
    }
    *(short8*)(Ktile[0] + row * 64 + ((p ^ (row & 7)) << 3)) = val;
  }
  __syncthreads();

  // ---- rel_lds[tl][j] = q[tl] . relk[j]   (log2-domain, q pre-scaled)
  #pragma unroll
  for (int qt = 0; qt < 2; qt++) {
    #pragma unroll
    for (int jt = 0; jt < 3; jt++) {
      floatx4 scR = (floatx4)(0.0f);
      #pragma unroll
      for (int ks = 0; ks < 2; ks++) {
        int rrow = jt * 16 + l16;
        int ck = (quad + 4 * ks) ^ (rrow & 7);
        short8 rb = *(const short8*)(Ktile[0] + rrow * 64 + ck * 8);
        scR = mfma16(aq[qt][ks], rb, scR);
      }
      int j = jt * 16 + l16;
      if (j < 33) {
        #pragma unroll
        for (int reg = 0; reg < 4; reg++) {
          int tl = qt * 128 + w * 16 + quad * 4 + reg;
          rel_lds[tl * 33 + j] = scR[reg];
        }
      }
    }
  }
  __syncthreads();   // rel_lds ready; Ktile free for K/V staging

  float biasLo[2], biasHi[2];
  #pragma unroll
  for (int qt = 0; qt < 2; qt++) {
    int ql = qt * 128 + w * 16 + l16;
    biasLo[qt] = rel_lds[ql * 33 + 0];
    biasHi[qt] = rel_lds[ql * 33 + 32];
  }

  floatx4 o[2][4];
  #pragma unroll
  for (int qt = 0; qt < 2; qt++)
    #pragma unroll
    for (int dt = 0; dt < 4; dt++) o[qt][dt] = (floatx4)(0.0f);
  floatx4 rsacc[2];
  rsacc[0] = (floatx4)(0.0f); rsacc[1] = (floatx4)(0.0f);
  short8 vone;
  #pragma unroll
  for (int i = 0; i < 8; i++) vone[i] = (short)0x3F80;   // bf16 1.0

  const short* kg = k_ws + (size_t)bh * 1024 * 64;
  const short* vg = v_ws + (size_t)bh * 64 * 1024;

  // K,V tiles: 64x64 bf16 = 512 16B-segs each -> 1 load/thread each.
  #define STAGE_KV(S0, BUF)                                                  \
    {                                                                        \
      int row = tid >> 3, p = tid & 7;                                       \
      int ck = p ^ (row & 7);                                                \
      async_copy16(kg + (size_t)((S0) + row) * 64 + ck * 8,                  \
                   Ktile[BUF] + (size_t)w * 512);                            \
      async_copy16(vg + (size_t)row * 1024 + (S0) + ck * 8,                  \
                   Vtile[BUF] + (size_t)w * 512);                            \
    }

  STAGE_KV(0, 0);

  for (int st = 0; st < 16; st++) {
    const int s0 = st * 64;
    const int cur = st & 1;
    __syncthreads();                // drains DMA(st); WAR for DMA(st+1)
    if (st < 15) STAGE_KV(s0 + 64, 1 - cur);

    bool diag[2]; float initv[2];
    #pragma unroll
    for (int qt = 0; qt < 2; qt++) {
      const int qbase = t0 + qt * 128 + w * 16;
      bool alllo = (s0 <= qbase - 79);
      bool allhi = (s0 >= qbase + 31);
      diag[qt] = !(alllo || allhi);
      initv[qt] = alllo ? biasLo[qt] : (allhi ? biasHi[qt] : 0.0f);
    }

    // ---- per nt: kb read ONCE, QK for both q-groups, exp2 + pack ----
    #pragma unroll
    for (int nt = 0; nt < 4; nt++) {
      short8 kb0, kb1;
      {
        int srow = nt * 16 + l16;
        kb0 = *(const short8*)(Ktile[cur] + srow * 64
                               + ((quad ^ (l16 & 7)) << 3));
        kb1 = *(const short8*)(Ktile[cur] + srow * 64
                               + (((quad + 4) ^ (l16 & 7)) << 3));
      }
      #pragma unroll
      for (int qt = 0; qt < 2; qt++) {
        floatx4 sc = (floatx4)(initv[qt]);
        __builtin_amdgcn_s_setprio(1);
        sc = mfma16(kb0, aq[qt][0], sc);
        sc = mfma16(kb1, aq[qt][1], sc);
        __builtin_amdgcn_s_setprio(0);
        if (diag[qt]) {
          int ql = qt * 128 + w * 16 + l16;
          const int qbase = t0 + qt * 128 + w * 16;
          #pragma unroll
          for (int reg = 0; reg < 4; reg++) {
            int delta = (s0 + 16 * nt + 4 * quad + reg) - (qbase + l16);
            delta = min(max(delta, -16), 16) + 16;
            sc[reg] += rel_lds[ql * 33 + delta];
          }
        }
        #pragma unroll
        for (int reg = 0; reg < 4; reg++) sc[reg] = exp2_hw(sc[reg]);
        unsigned w0 = pk_bf16(sc[0], sc[1]);
        unsigned w1 = pk_bf16(sc[2], sc[3]);
        int srot = (16 * nt + 4 * quad + 4 * l16) & 63;   // rotation swizzle
        *(uint2*)(p_lds[w * 2 + qt] + l16 * 64 + srot) = make_uint2(w0, w1);
      }
    }

    // ---- P A-fragments ----
    short8 ap[2][2];
    #pragma unroll
    for (int qt = 0; qt < 2; qt++)
      #pragma unroll
      for (int ks = 0; ks < 2; ks++) {
        int s1 = (32 * ks + 8 * quad + 4 * l16) & 63;
        int s2 = (s1 + 4) & 63;
        union { short8 v; uint2 u[2]; } pu;
        pu.u[0] = *(const uint2*)(p_lds[w * 2 + qt] + l16 * 64 + s1);
        pu.u[1] = *(const uint2*)(p_lds[w * 2 + qt] + l16 * 64 + s2);
        ap[qt][ks] = pu.v;
      }

    // ---- rsum via ones-MFMA + O += P V (vb read ONCE per dt) ----
    __builtin_amdgcn_s_setprio(1);
    #pragma unroll
    for (int qt = 0; qt < 2; qt++) {
      rsacc[qt] = mfma16(ap[qt][0], vone, rsacc[qt]);
      rsacc[qt] = mfma16(ap[qt][1], vone, rsacc[qt]);
    }
    #pragma unroll
    for (int dt = 0; dt < 4; dt++) {
      short8 vb0, vb1;
      {
        int drow = dt * 16 + l16;
        vb0 = *(const short8*)(Vtile[cur] + drow * 64
                               + ((quad ^ (l16 & 7)) << 3));
        vb1 = *(const short8*)(Vtile[cur] + drow * 64
                               + (((quad + 4) ^ (l16 & 7)) << 3));
      }
      #pragma unroll
      for (int qt = 0; qt < 2; qt++) {
        o[qt][dt] = mfma16(ap[qt][0], vb0, o[qt][dt]);
        o[qt][dt] = mfma16(ap[qt][1], vb1, o[qt][dt]);
      }
    }
    __builtin_amdgcn_s_setprio(0);
  }
  #undef STAGE_KV

  // ---- normalize + store: rsacc rows (q = quad*4+reg) match o rows ----
  #pragma unroll
  for (int qt = 0; qt < 2; qt++) {
    float inv_[4];
    #pragma unroll
    for (int reg = 0; reg < 4; reg++) inv_[reg] = 1.0f / rsacc[qt][reg];
    #pragma unroll
    for (int dt = 0; dt < 4; dt++) {
      unsigned u01 = pk_bf16(o[qt][dt][0] * inv_[0], o[qt][dt][1] * inv_[1]);
      unsigned u23 = pk_bf16(o[qt][dt][2] * inv_[2], o[qt][dt][3] * inv_[3]);
      int tg = t0 + qt * 128 + w * 16 + quad * 4;
      size_t base = ((size_t)tg * 4 + b) * 1024 + h * 64 + dt * 16 + l16;
      attn_ws[base]         = (short)u01;
      attn_ws[base + 4096]  = (short)(u01 >> 16);
      attn_ws[base + 8192]  = (short)u23;
      attn_ws[base + 12288] = (short)(u23 >> 16);
    }
  }
}

// ---------------------------------------------------------------------------
// Kernel 3: out = attn @ out_w^T + out_b, fp32 (T,B,E).
// R4-proven structure: 128x128 tile, BK=64, 512 thr (8 waves 2Mx4N,
// per-wave 64x32), grid (32,8) = 256 blocks = 1/CU, 64 KB LDS dbuf,
// xor-8 swizzle, 16 K-tiles with one vmcnt(0)+barrier drain each.
// ---------------------------------------------------------------------------
__global__ void __launch_bounds__(512, 2) gemm_outproj(
    const short* __restrict__ A, const short* __restrict__ W,
    const float* __restrict__ bias, float* __restrict__ out)
{
  __shared__ __align__(16) short Atile[2 * 128 * 64];   // 32 KB
  __shared__ __align__(16) short Btile[2 * 128 * 64];   // 32 KB
  const int tid = threadIdx.x, lane = tid & 63, w = tid >> 6;
  const int quad = lane >> 4, l16 = lane & 15;
  const int m0 = blockIdx.x * 128, n0 = blockIdx.y * 128;
  const int wmh = (w >> 2);             // 0/1: which 64-row half of A tile
  const int wn = (w & 3) * 32;          // wave's 32-col window in B tile

  const short* Ag = A + (size_t)m0 * 1024;
  const short* Wg = W + (size_t)n0 * 1024;

  floatx4 acc[4][2];
  #pragma unroll
  for (int mt = 0; mt < 4; mt++)
    #pragma unroll
    for (int nt = 0; nt < 2; nt++) acc[mt][nt] = (floatx4)(0.0f);

  // A,B: 128x64 bf16 = 1024 16B-segs each -> 2 loads/thread each.
  #define STAGE_OP(kc, buf)                                                  \
    {                                                                        \
      _Pragma("unroll")                                                      \
      for (int i = 0; i < 2; i++) {                                          \
        int seg = i * 512 + tid;                                             \
        int row = seg >> 3, p = seg & 7;                                     \
        int ck = p ^ (row & 7);                                              \
        async_copy16(Ag + (size_t)row * 1024 + (kc) * 64 + ck * 8,           \
                     Atile + (buf) * 8192 + (size_t)(i * 512 + w * 64) * 8); \
        async_copy16(Wg + (size_t)row * 1024 + (kc) * 64 + ck * 8,           \
                     Btile + (buf) * 8192 + (size_t)(i * 512 + w * 64) * 8); \
      }                                                                      \
    }

  STAGE_OP(0, 0);
  asm volatile("s_waitcnt vmcnt(0)" ::: "memory");
  __builtin_amdgcn_s_barrier();

  for (int kt = 0; kt < 16; ++kt) {
    const int cur = kt & 1, nxt = cur ^ 1;
    const int kc1 = (kt + 1 < 16) ? kt + 1 : 15;   // ghost re-stage on tail

    // ---- prefetch next tile FIRST ----
    STAGE_OP(kc1, nxt);

    // ---- fragment reads (12 x ds_read_b128) ----
    short8 af[4][2], bf[2][2];
    #pragma unroll
    for (int mt = 0; mt < 4; mt++) {
      int gr = wmh * 64 + mt * 16 + l16;            // 0..127
      #pragma unroll
      for (int ks = 0; ks < 2; ks++)
        af[mt][ks] = *(const short8*)(Atile + cur * 8192 + gr * 64
                                      + (((quad + 4 * ks) ^ (gr & 7)) << 3));
    }
    #pragma unroll
    for (int nt = 0; nt < 2; nt++) {
      int row = wn + nt * 16 + l16;                 // 0..127
      #pragma unroll
      for (int ks = 0; ks < 2; ks++)
        bf[nt][ks] = *(const short8*)(Btile + cur * 8192 + row * 64
                                      + (((quad + 4 * ks) ^ (row & 7)) << 3));
    }

    // ---- 16 MFMA ----
    __builtin_amdgcn_s_setprio(1);
    #pragma unroll
    for (int mt = 0; mt < 4; mt++)
      #pragma unroll
      for (int nt = 0; nt < 2; nt++)
        #pragma unroll
        for (int ks = 0; ks < 2; ks++)
          acc[mt][nt] = mfma16(af[mt][ks], bf[nt][ks], acc[mt][nt]);
    __builtin_amdgcn_s_setprio(0);
    __builtin_amdgcn_sched_barrier(0);

    asm volatile("s_waitcnt vmcnt(0)" ::: "memory");   // nxt landed
    __builtin_amdgcn_s_barrier();
  }
  #undef STAGE_OP

  #pragma unroll
  for (int nt = 0; nt < 2; nt++) {
    int f = n0 + wn + nt * 16 + l16;
    float bv = bias[f];
    #pragma unroll
    for (int mt = 0; mt < 4; mt++) {
      #pragma unroll
      for (int reg = 0; reg < 4; reg++) {
        int r = m0 + wmh * 64 + mt * 16 + quad * 4 + reg;
        out[(size_t)r * 1024 + f] = acc[mt][nt][reg] + bv;
      }
    }
  }
}

extern "C" void kernel_launch(void* const* d_in, const int* in_sizes, int n_in,
                              void* d_out, int out_size, void* d_ws, size_t ws_size,
                              hipStream_t stream) {
  const float* query = (const float*)d_in[0];   // (T,B,E) fp32
  const float* in_w  = (const float*)d_in[1];   // (3E,E)  fp32
  const float* in_b  = (const float*)d_in[2];   // (3E,)   fp32
  const float* relk  = (const float*)d_in[3];   // (33,E)  fp32
  const float* out_w = (const float*)d_in[4];   // (E,E)   fp32
  const float* out_b = (const float*)d_in[5];   // (E,)    fp32
  float* out = (float*)d_out;                   // (T,B,E) fp32

  short* qry_bf = (short*)d_ws;                         // (B,T,E) bf16  8MB
  short* win_bf = qry_bf + (size_t)4096 * 1024;         // 3072x1024 bf16  6MB
  short* wout_bf = win_bf + (size_t)3072 * 1024;        // 1024x1024 bf16  2MB
  short* q_ws   = wout_bf + (size_t)1024 * 1024;        // (64,1024,64) bf16  8MB
  short* k_ws   = q_ws + (size_t)64 * 1024 * 64;        // (64,1024,64) bf16  8MB
  short* v_ws   = k_ws + (size_t)64 * 1024 * 64;        // (64,64,1024) bf16  8MB
  short* att_ws = v_ws + (size_t)64 * 1024 * 64;        // (4096,1024)  bf16  8MB

  convert_all_kernel<<<4096, 256, 0, stream>>>(query, in_w, out_w,
                                               qry_bf, win_bf, wout_bf);
  gemm_qkv<<<dim3(16, 16), 512, 0, stream>>>(qry_bf, win_bf, in_b, q_ws, k_ws, v_ws);
  attn_kernel<<<256, 512, 0, stream>>>(q_ws, k_ws, v_ws, relk, att_ws);
  gemm_outproj<<<dim3(32, 8), 512, 0, stream>>>(att_ws, wout_bf, out_b, out);
}

// Round 8
// 163.670 us; speedup vs baseline: 1.0224x; 1.0224x over previous
//
#include <hip/hip_runtime.h>
#include <hip/hip_bf16.h>

typedef __attribute__((ext_vector_type(8))) short short8;
typedef __attribute__((ext_vector_type(4))) float floatx4;

// Problem constants: T=1024, B=4, E=1024, H=16, D=64, L=16
// Inputs/outputs fp32; internals bf16 MFMA with fp32 accumulation.
// Softmax runs in the exp2 domain: q is pre-scaled by 0.125*log2(e), so
// scores (qk + rel-bias) are already in log2 units and p = exp2(s).

#define QSCALE 0.18033688011112043f   // 0.125 * log2(e)

__device__ __forceinline__ short f2bf(float x) {
  union { float f; unsigned u; } cv; cv.f = x;
  unsigned u = cv.u + (0x7FFFu + ((cv.u >> 16) & 1u));  // RNE
  return (short)(u >> 16);
}

// gfx950 v_cvt_pk_bf16_f32 via hip_bf16 API: 1 VALU op per 2 values.
__device__ __forceinline__ unsigned pk_bf16(float a, float b) {
  union { __hip_bfloat162 h; unsigned u; } cv;
  cv.h = __float22bfloat162_rn(make_float2(a, b));
  return cv.u;
}

// v_exp_f32 computes 2^x directly.
__device__ __forceinline__ float exp2_hw(float x) {
  return __builtin_amdgcn_exp2f(x);
}

__device__ __forceinline__ floatx4 mfma16(short8 a, short8 b, floatx4 c) {
  return __builtin_amdgcn_mfma_f32_16x16x32_bf16(a, b, c, 0, 0, 0);
}

__device__ __forceinline__ void async_copy16(const void* g, void* l) {
  __builtin_amdgcn_global_load_lds((const __attribute__((address_space(1))) void*)g,
                                   (__attribute__((address_space(3))) void*)l, 16, 0, 0);
}

// ---------------------------------------------------------------------------
// Kernel 0: fp32 -> bf16 for query / in_proj_weight / out_w in ONE launch.
// query is ALSO transposed (T,B,E) -> (B,T,E).
// ---------------------------------------------------------------------------
__global__ void __launch_bounds__(256) convert_all_kernel(
    const float* __restrict__ s0, const float* __restrict__ s1,
    const float* __restrict__ s2,
    short* __restrict__ d0, short* __restrict__ d1, short* __restrict__ d2)
{
  int i = blockIdx.x * 256 + threadIdx.x;
  if (i < 524288) {               // query with transpose
    int e8 = i & 127, b = (i >> 7) & 3, t = i >> 9;
    const float4* s = (const float4*)s0 + (size_t)i * 2;
    float4 a = s[0], c = s[1];
    uint4 o = make_uint4(pk_bf16(a.x, a.y), pk_bf16(a.z, a.w),
                         pk_bf16(c.x, c.y), pk_bf16(c.z, c.w));
    *(uint4*)(d0 + (size_t)b * 1048576 + t * 1024 + e8 * 8) = o;
  } else {                        // weights, straight copy
    const float* src; short* dst; int off;
    if (i < 917504) { src = s1; dst = d1; off = i - 524288; }
    else            { src = s2; dst = d2; off = i - 917504; }
    const float4* s = (const float4*)src + (size_t)off * 2;
    float4 a = s[0], c = s[1];
    uint4 o = make_uint4(pk_bf16(a.x, a.y), pk_bf16(a.z, a.w),
                         pk_bf16(c.x, c.y), pk_bf16(c.z, c.w));
    *(uint4*)(dst + (size_t)off * 8) = o;
  }
}

// ---------------------------------------------------------------------------
// Kernel 1: qkv = query_bt @ in_proj_weight^T + bias.
// 256x192 tile, BK=64, 8 waves (2Mx4N; per-wave 128x48), grid (16,16) = 256
// blocks = exactly 1 per CU (full machine, LDS 112 KB).
// Simple proven 2-phase pipeline: per K-tile
//   {7x global_load_lds (nxt) | 22x ds_read_b128 (cur) | 48 MFMA |
//    vmcnt(0) | s_barrier}
// xor-8 swizzled LDS (conflict-free b128 reads). 'which' (q/k/v) is
// resolved per-nt (16-wide, uniform).
// ---------------------------------------------------------------------------
__global__ void __launch_bounds__(512, 2) gemm_qkv(
    const short* __restrict__ A, const short* __restrict__ W,
    const float* __restrict__ bias,
    short* __restrict__ q_ws, short* __restrict__ k_ws, short* __restrict__ v_ws)
{
  __shared__ __align__(16) short Atile[2 * 256 * 64];   // 64 KB
  __shared__ __align__(16) short Btile[2 * 192 * 64];   // 48 KB
  const int tid = threadIdx.x, lane = tid & 63, w = tid >> 6;
  const int quad = lane >> 4, l16 = lane & 15;
  const int m0 = blockIdx.x * 256, n0 = blockIdx.y * 192;
  const int wmh = (w >> 2);             // 0/1: which 128-row half of A tile
  const int wn = (w & 3) * 48;          // wave's 48-col window in B tile

  const short* Ag = A + (size_t)m0 * 1024;
  const short* Wg = W + (size_t)n0 * 1024;

  floatx4 acc[8][3];
  #pragma unroll
  for (int mt = 0; mt < 8; mt++)
    #pragma unroll
    for (int nt = 0; nt < 3; nt++) acc[mt][nt] = (floatx4)(0.0f);

  // A: 256x64 bf16 = 2048 16B-segs -> 4 loads/thread.
  // B: 192x64 bf16 = 1536 16B-segs -> 3 loads/thread.
  // seg s: row = s>>3, slot p = s&7 holds global chunk ck = p^(row&7).
  #define STAGE_A(kc, buf)                                                   \
    {                                                                        \
      _Pragma("unroll")                                                      \
      for (int i = 0; i < 4; i++) {                                          \
        int seg = i * 512 + tid;                                             \
        int row = seg >> 3, p = seg & 7;                                     \
        int ck = p ^ (row & 7);                                              \
        async_copy16(Ag + (size_t)row * 1024 + (kc) * 64 + ck * 8,           \
                     Atile + (buf) * 16384 + (size_t)(i * 512 + w * 64) * 8);\
      }                                                                      \
    }
  #define STAGE_B(kc, buf)                                                   \
    {                                                                        \
      _Pragma("unroll")                                                      \
      for (int i = 0; i < 3; i++) {                                          \
        int seg = i * 512 + tid;                                             \
        int row = seg >> 3, p = seg & 7;                                     \
        int ck = p ^ (row & 7);                                              \
        async_copy16(Wg + (size_t)row * 1024 + (kc) * 64 + ck * 8,           \
                     Btile + (buf) * 12288 + (size_t)(i * 512 + w * 64) * 8);\
      }                                                                      \
    }

  STAGE_A(0, 0); STAGE_B(0, 0);
  asm volatile("s_waitcnt vmcnt(0)" ::: "memory");
  __builtin_amdgcn_s_barrier();

  for (int kt = 0; kt < 16; ++kt) {
    const int cur = kt & 1, nxt = cur ^ 1;
    const int kc1 = (kt + 1 < 16) ? kt + 1 : 15;   // ghost re-stage on tail

    // ---- prefetch next tile FIRST (lands while we read + MFMA) ----
    STAGE_A(kc1, nxt); STAGE_B(kc1, nxt);

    // ---- all fragment reads for this tile (22 x ds_read_b128) ----
    short8 af[8][2], bf[3][2];
    #pragma unroll
    for (int mt = 0; mt < 8; mt++) {
      int r = mt * 16 + l16;                        // 0..127 in wave's half
      int gr = wmh * 128 + r;                       // global A-tile row
      #pragma unroll
      for (int ks = 0; ks < 2; ks++)
        af[mt][ks] = *(const short8*)(Atile + cur * 16384 + gr * 64
                                      + (((quad + 4 * ks) ^ (r & 7)) << 3));
    }
    #pragma unroll
    for (int nt = 0; nt < 3; nt++) {
      int row = wn + nt * 16 + l16;                 // 0..191 (wn mult of 48)
      #pragma unroll
      for (int ks = 0; ks < 2; ks++)
        bf[nt][ks] = *(const short8*)(Btile + cur * 12288 + row * 64
                                      + (((quad + 4 * ks) ^ (row & 7)) << 3));
    }

    // ---- 48 MFMA ----
    __builtin_amdgcn_s_setprio(1);
    #pragma unroll
    for (int mt = 0; mt < 8; mt++)
      #pragma unroll
      for (int nt = 0; nt < 3; nt++)
        #pragma unroll
        for (int ks = 0; ks < 2; ks++)
          acc[mt][nt] = mfma16(af[mt][ks], bf[nt][ks], acc[mt][nt]);
    __builtin_amdgcn_s_setprio(0);
    __builtin_amdgcn_sched_barrier(0);

    asm volatile("s_waitcnt vmcnt(0)" ::: "memory");   // nxt landed
    __builtin_amdgcn_s_barrier();
  }
  #undef STAGE_A
  #undef STAGE_B

  // ---- epilogue: which (q/k/v) resolved per nt (16-wide, uniform) ----
  #pragma unroll
  for (int nt = 0; nt < 3; nt++) {
    int f = n0 + wn + nt * 16 + l16;          // 0..3071
    float bv = bias[f];
    int which = f >> 10;                      // 0=q 1=k 2=v
    int h = (f >> 6) & 15;
    int d = f & 63;
    if (which == 2) {
      #pragma unroll
      for (int mt = 0; mt < 8; mt++) {
        int r0 = m0 + wmh * 128 + mt * 16 + quad * 4;   // row = b*1024 + t
        int t = r0 & 1023, bb = r0 >> 10;
        int bh = bb * 16 + h;
        unsigned lo = pk_bf16(acc[mt][nt][0] + bv, acc[mt][nt][1] + bv);
        unsigned hi = pk_bf16(acc[mt][nt][2] + bv, acc[mt][nt][3] + bv);
        *(uint2*)(v_ws + ((size_t)bh * 64 + d) * 1024 + t) = make_uint2(lo, hi);
      }
    } else {
      short* dst = which ? k_ws : q_ws;
      const float sc = which ? 1.0f : QSCALE;
      #pragma unroll
      for (int mt = 0; mt < 8; mt++) {
        int r0 = m0 + wmh * 128 + mt * 16 + quad * 4;
        int t = r0 & 1023, bb = r0 >> 10;
        int bh = bb * 16 + h;
        unsigned u01 = pk_bf16((acc[mt][nt][0] + bv) * sc, (acc[mt][nt][1] + bv) * sc);
        unsigned u23 = pk_bf16((acc[mt][nt][2] + bv) * sc, (acc[mt][nt][3] + bv) * sc);
        size_t base = ((size_t)bh * 1024 + t) * 64 + d;
        dst[base]           = (short)u01;
        dst[base + 64]      = (short)(u01 >> 16);
        dst[base + 128]     = (short)u23;
        dst[base + 192]     = (short)(u23 >> 16);
      }
    }
  }
}

// ---------------------------------------------------------------------------
// Kernel 2: flash-style attention, S^T formulation.  (R6-measured-best)
// 512 threads (8 waves x 16 q-rows), grid 512, 66 KB LDS -> 2 blocks/CU
// = 16 waves/CU. Inter-block overlap hides per-s-tile barrier/DMA drain
// (1-block/CU variant measured slower: no co-resident block to cover the
// sync window).
//  - rsum via ones-MFMA (rsacc row layout == o row layout -> no shfl reduce)
//  - rel-bias folded into QK accumulator init on uniform tiles
//  - K/V double-buffered, one barrier per s-tile; XCD head-affinity swizzle
//  - exp2-domain softmax; T5 setprio around MFMA clusters
// ---------------------------------------------------------------------------
__global__ void __launch_bounds__(512, 4) attn_kernel(
    const short* __restrict__ q_ws, const short* __restrict__ k_ws,
    const short* __restrict__ v_ws, const float* __restrict__ relk,
    short* __restrict__ attn_ws)
{
  __shared__ float rel_lds[128 * 33];                   // 16896 B
  __shared__ __align__(16) short Ktile[2][64 * 64];     // 16384 B
  __shared__ __align__(16) short Vtile[2][64 * 64];     // 16384 B
  __shared__ __align__(16) short p_lds[8][16 * 64];     // 16384 B
  const int tid = threadIdx.x, lane = tid & 63, w = tid >> 6;  // w 0..7
  const int quad = lane >> 4, l16 = lane & 15;
  // XCD swizzle: head = 8*(blk&7) + (blk>>3)&7, chunk = blk>>6
  const int bh = 8 * ((int)blockIdx.x & 7) + (((int)blockIdx.x >> 3) & 7);
  const int t0 = ((int)blockIdx.x >> 6) * 128;
  const int b = bh >> 4, h = bh & 15;

  // Q fragments: q-row = t0 + w*16 + l16
  short8 aq[2];
  #pragma unroll
  for (int ks = 0; ks < 2; ks++)
    aq[ks] = *(const short8*)(q_ws
        + ((size_t)bh * 1024 + t0 + w * 16 + l16) * 64 + ks * 32 + quad * 8);

  // ---- stage relk[0:33][0:64] as bf16 into Ktile[0] (xor-swizzled, pad 48)
  if (tid < 384) {
    int row = tid >> 3, p = tid & 7;
    short8 val;
    if (row < 33) {
      const float* src = relk + row * 1024 + p * 8;
      float4 a = *(const float4*)src, c = *(const float4*)(src + 4);
      val[0] = f2bf(a.x); val[1] = f2bf(a.y); val[2] = f2bf(a.z); val[3] = f2bf(a.w);
      val[4] = f2bf(c.x); val[5] = f2bf(c.y); val[6] = f2bf(c.z); val[7] = f2bf(c.w);
    } else {
      val = (short8)0;
    }
    *(short8*)(Ktile[0] + row * 64 + ((p ^ (row & 7)) << 3)) = val;
  }
  __syncthreads();

  // ---- rel_lds[tl][j] = q[tl] . relk[j]   (log2-domain, q pre-scaled)
  #pragma unroll
  for (int jt = 0; jt < 3; jt++) {
    floatx4 scR = (floatx4)(0.0f);
    #pragma unroll
    for (int ks = 0; ks < 2; ks++) {
      int rrow = jt * 16 + l16;
      int ck = (quad + 4 * ks) ^ (rrow & 7);
      short8 rb = *(const short8*)(Ktile[0] + rrow * 64 + ck * 8);
      scR = mfma16(aq[ks], rb, scR);
    }
    int j = jt * 16 + l16;
    if (j < 33) {
      #pragma unroll
      for (int reg = 0; reg < 4; reg++) {
        int tl = w * 16 + quad * 4 + reg;
        rel_lds[tl * 33 + j] = scR[reg];
      }
    }
  }
  __syncthreads();   // rel_lds ready; Ktile free for K/V staging

  const float biasLo = rel_lds[(w * 16 + l16) * 33 + 0];
  const float biasHi = rel_lds[(w * 16 + l16) * 33 + 32];

  floatx4 o[4];
  #pragma unroll
  for (int dt = 0; dt < 4; dt++) o[dt] = (floatx4)(0.0f);
  floatx4 rsacc = (floatx4)(0.0f);       // row-sum accumulator (ones-MFMA)
  short8 vone;
  #pragma unroll
  for (int i = 0; i < 8; i++) vone[i] = (short)0x3F80;   // bf16 1.0

  const short* kg = k_ws + (size_t)bh * 1024 * 64;
  const short* vg = v_ws + (size_t)bh * 64 * 1024;

  // K,V tiles: 64x64 bf16 = 512 16B-segs each -> 1 load/thread each.
  #define STAGE_KV(S0, BUF)                                                  \
    {                                                                        \
      int row = tid >> 3, p = tid & 7;                                       \
      int ck = p ^ (row & 7);                                                \
      async_copy16(kg + (size_t)((S0) + row) * 64 + ck * 8,                  \
                   Ktile[BUF] + (size_t)w * 512);                            \
      async_copy16(vg + (size_t)row * 1024 + (S0) + ck * 8,                  \
                   Vtile[BUF] + (size_t)w * 512);                            \
    }

  STAGE_KV(0, 0);

  for (int st = 0; st < 16; st++) {
    const int s0 = st * 64;
    const int cur = st & 1;
    __syncthreads();                // drains DMA(st); WAR for DMA(st+1)
    if (st < 15) STAGE_KV(s0 + 64, 1 - cur);

    const int qbase = t0 + w * 16;
    const bool alllo = (s0 <= qbase - 79);
    const bool allhi = (s0 >= qbase + 31);
    const bool diag = !(alllo || allhi);
    const float initv = alllo ? biasLo : (allhi ? biasHi : 0.0f);

    // ---- per nt: QK MFMA (bias-folded C-init) + rel + exp2 + pack ----
    #pragma unroll
    for (int nt = 0; nt < 4; nt++) {
      short8 kb0, kb1;
      {
        int srow = nt * 16 + l16;
        kb0 = *(const short8*)(Ktile[cur] + srow * 64
                               + ((quad ^ (l16 & 7)) << 3));
        kb1 = *(const short8*)(Ktile[cur] + srow * 64
                               + ((((quad + 4)) ^ (l16 & 7)) << 3));
      }
      floatx4 sc = (floatx4)(initv);
      __builtin_amdgcn_s_setprio(1);
      sc = mfma16(kb0, aq[0], sc);
      sc = mfma16(kb1, aq[1], sc);
      __builtin_amdgcn_s_setprio(0);
      if (diag) {
        int ql = w * 16 + l16;
        #pragma unroll
        for (int reg = 0; reg < 4; reg++) {
          int delta = (s0 + 16 * nt + 4 * quad + reg) - (qbase + l16);
          delta = min(max(delta, -16), 16) + 16;
          sc[reg] += rel_lds[ql * 33 + delta];
        }
      }
      #pragma unroll
      for (int reg = 0; reg < 4; reg++) sc[reg] = exp2_hw(sc[reg]);
      unsigned w0 = pk_bf16(sc[0], sc[1]);
      unsigned w1 = pk_bf16(sc[2], sc[3]);
      int srot = (16 * nt + 4 * quad + 4 * l16) & 63;   // rotation swizzle
      *(uint2*)(p_lds[w] + l16 * 64 + srot) = make_uint2(w0, w1);
    }

    // ---- P A-fragments ----
    short8 ap[2];
    #pragma unroll
    for (int ks = 0; ks < 2; ks++) {
      int s1 = (32 * ks + 8 * quad + 4 * l16) & 63;
      int s2 = (s1 + 4) & 63;
      union { short8 v; uint2 u[2]; } pu;
      pu.u[0] = *(const uint2*)(p_lds[w] + l16 * 64 + s1);
      pu.u[1] = *(const uint2*)(p_lds[w] + l16 * 64 + s2);
      ap[ks] = pu.v;
    }

    // ---- rsum via ones-MFMA + O += P V ----
    __builtin_amdgcn_s_setprio(1);
    rsacc = mfma16(ap[0], vone, rsacc);
    rsacc = mfma16(ap[1], vone, rsacc);
    #pragma unroll
    for (int dt = 0; dt < 4; dt++) {
      short8 vb0, vb1;
      {
        int drow = dt * 16 + l16;
        vb0 = *(const short8*)(Vtile[cur] + drow * 64
                               + ((quad ^ (l16 & 7)) << 3));
        vb1 = *(const short8*)(Vtile[cur] + drow * 64
                               + (((quad + 4) ^ (l16 & 7)) << 3));
      }
      o[dt] = mfma16(ap[0], vb0, o[dt]);
      o[dt] = mfma16(ap[1], vb1, o[dt]);
    }
    __builtin_amdgcn_s_setprio(0);
  }
  #undef STAGE_KV

  // ---- normalize + store: rsacc rows (q = quad*4+reg) match o rows ----
  float inv_[4];
  #pragma unroll
  for (int reg = 0; reg < 4; reg++) inv_[reg] = 1.0f / rsacc[reg];
  #pragma unroll
  for (int dt = 0; dt < 4; dt++) {
    unsigned u01 = pk_bf16(o[dt][0] * inv_[0], o[dt][1] * inv_[1]);
    unsigned u23 = pk_bf16(o[dt][2] * inv_[2], o[dt][3] * inv_[3]);
    int tg = t0 + w * 16 + quad * 4;
    size_t base = ((size_t)tg * 4 + b) * 1024 + h * 64 + dt * 16 + l16;
    attn_ws[base]         = (short)u01;
    attn_ws[base + 4096]  = (short)(u01 >> 16);
    attn_ws[base + 8192]  = (short)u23;
    attn_ws[base + 12288] = (short)(u23 >> 16);
  }
}

// ---------------------------------------------------------------------------
// Kernel 3: out = attn @ out_w^T + out_b, fp32 (T,B,E).
// R4-proven structure: 128x128 tile, BK=64, 512 thr (8 waves 2Mx4N,
// per-wave 64x32), grid (32,8) = 256 blocks = 1/CU, 64 KB LDS dbuf,
// xor-8 swizzle, 16 K-tiles with one vmcnt(0)+barrier drain each.
// ---------------------------------------------------------------------------
__global__ void __launch_bounds__(512, 2) gemm_outproj(
    const short* __restrict__ A, const short* __restrict__ W,
    const float* __restrict__ bias, float* __restrict__ out)
{
  __shared__ __align__(16) short Atile[2 * 128 * 64];   // 32 KB
  __shared__ __align__(16) short Btile[2 * 128 * 64];   // 32 KB
  const int tid = threadIdx.x, lane = tid & 63, w = tid >> 6;
  const int quad = lane >> 4, l16 = lane & 15;
  const int m0 = blockIdx.x * 128, n0 = blockIdx.y * 128;
  const int wmh = (w >> 2);             // 0/1: which 64-row half of A tile
  const int wn = (w & 3) * 32;          // wave's 32-col window in B tile

  const short* Ag = A + (size_t)m0 * 1024;
  const short* Wg = W + (size_t)n0 * 1024;

  floatx4 acc[4][2];
  #pragma unroll
  for (int mt = 0; mt < 4; mt++)
    #pragma unroll
    for (int nt = 0; nt < 2; nt++) acc[mt][nt] = (floatx4)(0.0f);

  // A,B: 128x64 bf16 = 1024 16B-segs each -> 2 loads/thread each.
  #define STAGE_OP(kc, buf)                                                  \
    {                                                                        \
      _Pragma("unroll")                                                      \
      for (int i = 0; i < 2; i++) {                                          \
        int seg = i * 512 + tid;                                             \
        int row = seg >> 3, p = seg & 7;                                     \
        int ck = p ^ (row & 7);                                              \
        async_copy16(Ag + (size_t)row * 1024 + (kc) * 64 + ck * 8,           \
                     Atile + (buf) * 8192 + (size_t)(i * 512 + w * 64) * 8); \
        async_copy16(Wg + (size_t)row * 1024 + (kc) * 64 + ck * 8,           \
                     Btile + (buf) * 8192 + (size_t)(i * 512 + w * 64) * 8); \
      }                                                                      \
    }

  STAGE_OP(0, 0);
  asm volatile("s_waitcnt vmcnt(0)" ::: "memory");
  __builtin_amdgcn_s_barrier();

  for (int kt = 0; kt < 16; ++kt) {
    const int cur = kt & 1, nxt = cur ^ 1;
    const int kc1 = (kt + 1 < 16) ? kt + 1 : 15;   // ghost re-stage on tail

    // ---- prefetch next tile FIRST ----
    STAGE_OP(kc1, nxt);

    // ---- fragment reads (12 x ds_read_b128) ----
    short8 af[4][2], bf[2][2];
    #pragma unroll
    for (int mt = 0; mt < 4; mt++) {
      int gr = wmh * 64 + mt * 16 + l16;            // 0..127
      #pragma unroll
      for (int ks = 0; ks < 2; ks++)
        af[mt][ks] = *(const short8*)(Atile + cur * 8192 + gr * 64
                                      + (((quad + 4 * ks) ^ (gr & 7)) << 3));
    }
    #pragma unroll
    for (int nt = 0; nt < 2; nt++) {
      int row = wn + nt * 16 + l16;                 // 0..127
      #pragma unroll
      for (int ks = 0; ks < 2; ks++)
        bf[nt][ks] = *(const short8*)(Btile + cur * 8192 + row * 64
                                      + (((quad + 4 * ks) ^ (row & 7)) << 3));
    }

    // ---- 16 MFMA ----
    __builtin_amdgcn_s_setprio(1);
    #pragma unroll
    for (int mt = 0; mt < 4; mt++)
      #pragma unroll
      for (int nt = 0; nt < 2; nt++)
        #pragma unroll
        for (int ks = 0; ks < 2; ks++)
          acc[mt][nt] = mfma16(af[mt][ks], bf[nt][ks], acc[mt][nt]);
    __builtin_amdgcn_s_setprio(0);
    __builtin_amdgcn_sched_barrier(0);

    asm volatile("s_waitcnt vmcnt(0)" ::: "memory");   // nxt landed
    __builtin_amdgcn_s_barrier();
  }
  #undef STAGE_OP

  #pragma unroll
  for (int nt = 0; nt < 2; nt++) {
    int f = n0 + wn + nt * 16 + l16;
    float bv = bias[f];
    #pragma unroll
    for (int mt = 0; mt < 4; mt++) {
      #pragma unroll
      for (int reg = 0; reg < 4; reg++) {
        int r = m0 + wmh * 64 + mt * 16 + quad * 4 + reg;
        out[(size_t)r * 1024 + f] = acc[mt][nt][reg] + bv;
      }
    }
  }
}

extern "C" void kernel_launch(void* const* d_in, const int* in_sizes, int n_in,
                              void* d_out, int out_size, void* d_ws, size_t ws_size,
                              hipStream_t stream) {
  const float* query = (const float*)d_in[0];   // (T,B,E) fp32
  const float* in_w  = (const float*)d_in[1];   // (3E,E)  fp32
  const float* in_b  = (const float*)d_in[2];   // (3E,)   fp32
  const float* relk  = (const float*)d_in[3];   // (33,E)  fp32
  const float* out_w = (const float*)d_in[4];   // (E,E)   fp32
  const float* out_b = (const float*)d_in[5];   // (E,)    fp32
  float* out = (float*)d_out;                   // (T,B,E) fp32

  short* qry_bf = (short*)d_ws;                         // (B,T,E) bf16  8MB
  short* win_bf = qry_bf + (size_t)4096 * 1024;         // 3072x1024 bf16  6MB
  short* wout_bf = win_bf + (size_t)3072 * 1024;        // 1024x1024 bf16  2MB
  short* q_ws   = wout_bf + (size_t)1024 * 1024;        // (64,1024,64) bf16  8MB
  short* k_ws   = q_ws + (size_t)64 * 1024 * 64;        // (64,1024,64) bf16  8MB
  short* v_ws   = k_ws + (size_t)64 * 1024 * 64;        // (64,64,1024) bf16  8MB
  short* att_ws = v_ws + (size_t)64 * 1024 * 64;        // (4096,1024)  bf16  8MB

  convert_all_kernel<<<4096, 256, 0, stream>>>(query, in_w, out_w,
                                               qry_bf, win_bf, wout_bf);
  gemm_qkv<<<dim3(16, 16), 512, 0, stream>>>(qry_bf, win_bf, in_b, q_ws, k_ws, v_ws);
  attn_kernel<<<512, 512, 0, stream>>>(q_ws, k_ws, v_ws, relk, att_ws);
  gemm_outproj<<<dim3(32, 8), 512, 0, stream>>>(att_ws, wout_bf, out_b, out);
}